// Round 2
// baseline (131.541 us; speedup 1.0000x reference)
//
#include <hip/hip_runtime.h>
#include <hip/hip_bf16.h>

#define LN_EPS 1e-5f
#define BB 32        // batch
#define NI 200       // attended nodes
#define DD 64        // feature dim

typedef __attribute__((ext_vector_type(8))) short bf16x8;
typedef __attribute__((ext_vector_type(4))) short bf16x4;
typedef __attribute__((ext_vector_type(4))) float f32x4;

__device__ __forceinline__ float leaky(float x) { return fmaxf(x, 0.01f * x); }
__device__ __forceinline__ short f2bf(float x) {
  __hip_bfloat16 h = __float2bfloat16(x);
  return *reinterpret_cast<short*>(&h);
}
__device__ __forceinline__ float bf2fs(short s) {
  unsigned u = ((unsigned)(unsigned short)s) << 16;
  return __uint_as_float(u);
}

__device__ __forceinline__ void reduce2(float& a, float& b) {
#pragma unroll
  for (int m = 1; m < 64; m <<= 1) { a += __shfl_xor(a, m, 64); b += __shfl_xor(b, m, 64); }
}
__device__ __forceinline__ void reduce4(float& a, float& b, float& c, float& d) {
#pragma unroll
  for (int m = 1; m < 64; m <<= 1) {
    a += __shfl_xor(a, m, 64); b += __shfl_xor(b, m, 64);
    c += __shfl_xor(c, m, 64); d += __shfl_xor(d, m, 64);
  }
}
__device__ __forceinline__ float reduce1(float a) {
#pragma unroll
  for (int m = 1; m < 64; m <<= 1) a += __shfl_xor(a, m, 64);
  return a;
}
__device__ __forceinline__ void rmax2(float& a, float& b) {
#pragma unroll
  for (int m = 1; m < 64; m <<= 1) {
    a = fmaxf(a, __shfl_xor(a, m, 64));
    b = fmaxf(b, __shfl_xor(b, m, 64));
  }
}

// ---------------- LDS carve (bytes) ----------------
// SM_G region is time-shared: phases 0-1 use it as sY = f32[202 rows][stride 65]
// (LN output, +1-pad stride kills column bank conflicts); phase 3 reuses it as
// 8 wave-private G frag buffers (7168 B each). sY is dead by then.
#define SM_G    0         // 57344 B
#define SM_UA   57344     // 26624 B  bf16 node-major frags (13 it x 2 kh x 64 lanes x 8)
#define SM_UA2  83968     // 26624 B  squared frags (precomputed once)
#define SM_UAT  110592    // 28672 B  bf16 d-major frags (7 p x 4 dt x 64 lanes x 8)
#define SM_ST   139264    // 4992 B   f32[208][6] {base1,rm1,rden1,base2,rm2,rden2}
#define SM_KV   144256    // 1664 B   f32[2][208] sk per head
#define SM_V    145920    // 1536 B   f32[6][64]  {v1q,v1k,v2q,v2k,vi1,vi2}
#define SM_MS   147456    // 1024 B   f32[8 waves][2][16] wave-private m/S per j
#define SM_WMX  148480    // 64 B     f32[8][2] per-wave sk maxes
#define SM_MISC 148544    // 32 B     c0..c5, t1full, t2full
#define SM_TOTAL 148576

// One block per batch element b. 512 threads = 8 waves.
// Phase 0: LN all 202 rows -> sY; wave-specialized W-projections + creds.
// Phase 1: build ua frags (+squares, +d-major), score dots, t-dots, out row 0.
// Phase 2: block max of sk, per-(i,head) softmax stats.
// Phase 3: per wave: j-tile jt -> S/T MFMAs + epilogue -> wave-private G,
//          then H = G^T * UA + output epilogue. No barrier needed inside
//          (G and m/S buffers are wave-private; same-wave LDS ordering).
__global__ void __launch_bounds__(512, 1)
gat_fused(const float* __restrict__ emb,
          const float* __restrict__ lw,
          const float* __restrict__ lb,
          const float* __restrict__ W1,
          const float* __restrict__ W1b,
          const float* __restrict__ W2,
          const float* __restrict__ W2b,
          const float* __restrict__ a1,
          const float* __restrict__ a1b,
          const float* __restrict__ a2,
          const float* __restrict__ a2b,
          float* __restrict__ out) {
  __shared__ __align__(16) char smem[SM_TOTAL];
  float* sY   = (float*)(smem + SM_G);
  short* sG   = (short*)(smem + SM_G);
  short* sUA  = (short*)(smem + SM_UA);
  short* sUA2 = (short*)(smem + SM_UA2);
  short* sUAT = (short*)(smem + SM_UAT);
  float* sST  = (float*)(smem + SM_ST);
  float* sKV  = (float*)(smem + SM_KV);
  float* sV   = (float*)(smem + SM_V);
  float* sMS  = (float*)(smem + SM_MS);
  float* wmx  = (float*)(smem + SM_WMX);
  float* sMisc = (float*)(smem + SM_MISC);

  int b = blockIdx.x, tid = threadIdx.x, wv = tid >> 6, lane = tid & 63;
  int q = lane >> 4, col = lane & 15;

  // ---- phase 0: LayerNorm all rows + projections ----
  {
    float w = lw[lane], bi = lb[lane];
    for (int n = wv; n < 202; n += 8) {
      float x = emb[(size_t)(b * 202 + n) * 64 + lane];
      float s = x, s2 = x * x;
      reduce2(s, s2);
      float mu = s * (1.f / 64);
      float var = fmaxf(s2 * (1.f / 64) - mu * mu, 0.f);
      sY[n * 65 + lane] = (x - mu) * rsqrtf(var + LN_EPS) * w + bi;
    }
  }
  if (wv == 0) {
    float p0 = 0, p1 = 0;
#pragma unroll 8
    for (int d = 0; d < 64; d++) {
      float x = W1[d * 64 + lane];
      p0 = fmaf(x, a1[d], p0); p1 = fmaf(x, a1[64 + d], p1);
    }
    sV[0 * 64 + lane] = p0; sV[1 * 64 + lane] = p1;
  } else if (wv == 1) {
    float p0 = 0, p1 = 0;
#pragma unroll 8
    for (int d = 0; d < 64; d++) {
      float x = W2[d * 64 + lane];
      p0 = fmaf(x, a2[d], p0); p1 = fmaf(x, a2[64 + d], p1);
    }
    sV[2 * 64 + lane] = p0; sV[3 * 64 + lane] = p1;
  } else if (wv == 2) {
    float p = 0;
#pragma unroll 8
    for (int d = 0; d < 64; d++) p = fmaf(W1[d * 64 + lane], a1[128 + d], p);
    sV[4 * 64 + lane] = p;
    float c0 = reduce1(W1b[lane] * a1[lane]);
    float c1 = reduce1(W1b[lane] * a1[64 + lane]);
    float c2 = reduce1(W1b[lane] * a1[128 + lane]);
    if (lane == 0) { sMisc[0] = c0; sMisc[1] = c1; sMisc[2] = c2; }
  } else if (wv == 3) {
    float p = 0;
#pragma unroll 8
    for (int d = 0; d < 64; d++) p = fmaf(W2[d * 64 + lane], a2[128 + d], p);
    sV[5 * 64 + lane] = p;
    float c3 = reduce1(W2b[lane] * a2[lane]);
    float c4 = reduce1(W2b[lane] * a2[64 + lane]);
    float c5 = reduce1(W2b[lane] * a2[128 + lane]);
    if (lane == 0) { sMisc[3] = c3; sMisc[4] = c4; sMisc[5] = c5; }
  }
  __syncthreads();

  // ---- phase 1: ua frags, score dots, t-dots, out row 0, pad init ----
  if (wv == 0) {
    float u0 = sY[0 * 65 + lane];
    float iid = sY[1 * 65 + lane];
    out[(size_t)(b * 201) * 64 + lane] = leaky(u0 * iid);
    float q0 = iid * sV[4 * 64 + lane], q1 = iid * sV[5 * 64 + lane];
    reduce2(q0, q1);
    if (lane == 0) {
      sMisc[6] = q0 + sMisc[2] + a1b[0];   // t1 = iid.vi1 + c2 + ab1
      sMisc[7] = q1 + sMisc[5] + a2b[0];   // t2 = iid.vi2 + c5 + ab2
    }
  }
  // node-major frags + squared frags (squares of the bf16-rounded value,
  // matching the old sq8 numerics exactly)
  for (int idx = tid; idx < 1664; idx += 512) {
    int itile = idx >> 7, rem = idx & 127, kh = rem >> 6, ln = rem & 63;
    int node = itile * 16 + (ln & 15);
    int dbase = kh * 32 + (ln >> 4) * 8;
    bf16x8 pk, pk2;
    if (node < NI) {
      const float* yr = sY + (2 + node) * 65 + dbase;
#pragma unroll
      for (int k = 0; k < 8; k++) {
        float v = sY[dbase + k] * yr[k];      // u[d] * ln[node][d]
        short h = f2bf(v);
        pk[k] = h;
        float f = bf2fs(h);
        pk2[k] = f2bf(f * f);
      }
    } else {
#pragma unroll
      for (int k = 0; k < 8; k++) { pk[k] = 0; pk2[k] = 0; }
    }
    *(bf16x8*)(sUA + idx * 8) = pk;
    *(bf16x8*)(sUA2 + idx * 8) = pk2;
  }
  // d-major frags
  {
    int d = tid & 63, ir = (tid >> 6) & 3, ph = tid >> 8;
    float ud = sY[d];
    for (int p = ph; p < 7; p += 2) {
      int i0 = p * 32 + ir * 8;
      bf16x8 pk;
#pragma unroll
      for (int uu = 0; uu < 8; uu++) {
        int node = i0 + uu;
        pk[uu] = (node < NI) ? f2bf(ud * sY[(2 + node) * 65 + d]) : (short)0;
      }
      int off = ((p * 4 + (d >> 4)) * 64 + ((d & 15) + 16 * ir)) * 8;
      *(bf16x8*)(sUAT + off) = pk;
    }
  }
  // score dots: sq/sk per head (f32 ua, as before)
  {
    float u0 = sY[lane];
    for (int i = wv; i < NI; i += 8) {
      float a = u0 * sY[(2 + i) * 65 + lane];
      float p0 = a * sV[0 * 64 + lane], p1 = a * sV[1 * 64 + lane];
      float p2 = a * sV[2 * 64 + lane], p3 = a * sV[3 * 64 + lane];
      reduce4(p0, p1, p2, p3);
      if (lane == 0) {
        sST[i * 6 + 0] = p0 + sMisc[0];   // sq1 + c0 (t1 added in phase 2)
        sST[i * 6 + 3] = p2 + sMisc[3];   // sq2 + c3
        sKV[0 * 208 + i] = p1 + sMisc[1]; // sk1 + c1
        sKV[1 * 208 + i] = p3 + sMisc[4]; // sk2 + c4
      }
    }
  }
  // pad rows 200..207: zero stats (-> g=0) and zero sk (finite)
  if (tid < 48) sST[1200 + tid] = 0.f;
  if (tid < 16) sKV[(tid >> 3) * 208 + 200 + (tid & 7)] = 0.f;
  __syncthreads();

  // ---- phase 2: block max + softmax stats ----
  {
    float m1 = (tid < NI) ? sKV[tid] : -3e38f;
    float m2 = (tid < NI) ? sKV[208 + tid] : -3e38f;
    rmax2(m1, m2);
    if (lane == 0) { wmx[wv * 2] = m1; wmx[wv * 2 + 1] = m2; }
  }
  __syncthreads();
  {
    int sh = -1, si = 0;
    if (tid < NI) { sh = 0; si = tid; }
    else if (tid >= 256 && tid < 256 + NI) { sh = 1; si = tid - 256; }
    if (sh >= 0) {
      float mx = -3e38f;
#pragma unroll
      for (int k = 0; k < 8; k++) mx = fmaxf(mx, wmx[k * 2 + sh]);
      float* st = sST + si * 6;
      float base = st[sh * 3] + sMisc[6 + sh];   // add t-term
      st[sh * 3] = base;
      float rm = leaky(base + mx);               // leaky monotone
      const float* skh = sKV + sh * 208;
      float den = 0.f;
#pragma unroll 4
      for (int j = 0; j < NI; j++) {
        float s = base + skh[j];
        den += __expf(fmaxf(s, 0.01f * s) - rm);
      }
      st[sh * 3 + 1] = rm;
      st[sh * 3 + 2] = 1.0f / den;
    }
  }
  __syncthreads();

  // ---- phase 3: per-wave j-tiles, A (S/T + g) then B (H + output) ----
  short* sGw = sG + wv * 3584;     // 7168 B wave-private
  float* sMSw = sMS + wv * 32;     // [2][16] wave-private
  for (int p = 0; p < 2; p++) {
    int jt = wv + 8 * p;
    if (jt >= 13) break;
    {
      bf16x8 z;
#pragma unroll
      for (int k = 0; k < 8; k++) z[k] = 0;
      if (lane >= 32) *(bf16x8*)(sGw + (6 * 64 + lane) * 8) = z;  // k-tail i=208..223
    }
    bf16x8 bf0 = *(bf16x8*)(sUA + ((jt * 2 + 0) * 64 + lane) * 8);
    bf16x8 bf1 = *(bf16x8*)(sUA + ((jt * 2 + 1) * 64 + lane) * 8);
    bf16x8 b2f0 = *(bf16x8*)(sUA2 + ((jt * 2 + 0) * 64 + lane) * 8);
    bf16x8 b2f1 = *(bf16x8*)(sUA2 + ((jt * 2 + 1) * 64 + lane) * 8);
    int jglob = jt * 16 + col;
    float skj1 = sKV[jglob], skj2 = sKV[208 + jglob];
    float mpart = 0.f, spart = 0.f;
    for (int it = 0; it < 13; it++) {
      bf16x8 af0 = *(bf16x8*)(sUA + ((it * 2 + 0) * 64 + lane) * 8);
      bf16x8 af1 = *(bf16x8*)(sUA + ((it * 2 + 1) * 64 + lane) * 8);
      bf16x8 a2f0 = *(bf16x8*)(sUA2 + ((it * 2 + 0) * 64 + lane) * 8);
      bf16x8 a2f1 = *(bf16x8*)(sUA2 + ((it * 2 + 1) * 64 + lane) * 8);
      f32x4 s = {0, 0, 0, 0}, t = {0, 0, 0, 0};
      s = __builtin_amdgcn_mfma_f32_16x16x32_bf16(af0, bf0, s, 0, 0, 0);
      s = __builtin_amdgcn_mfma_f32_16x16x32_bf16(af1, bf1, s, 0, 0, 0);
      t = __builtin_amdgcn_mfma_f32_16x16x32_bf16(a2f0, b2f0, t, 0, 0, 0);
      t = __builtin_amdgcn_mfma_f32_16x16x32_bf16(a2f1, b2f1, t, 0, 0, 0);
      bf16x4 gp;
#pragma unroll
      for (int r = 0; r < 4; r++) {
        int i = it * 16 + q * 4 + r;
        const float* st = sST + i * 6;
        float mu = s[r] * (1.f / 64);
        float var = fmaxf(t[r] * (1.f / 64) - mu * mu, 0.f);
        float inv = rsqrtf(var + LN_EPS);
        float sc1 = st[0] + skj1;
        float e1 = __expf(fmaxf(sc1, 0.01f * sc1) - st[1]) * st[2];
        float sc2 = st[3] + skj2;
        float e2 = __expf(fmaxf(sc2, 0.01f * sc2) - st[4]) * st[5];
        float c = 0.5f * (e1 + e2);
        float g = c * inv;
        mpart = fmaf(g, mu, mpart);
        spart += c;
        gp[r] = f2bf(g);
      }
      int kl = (it & 1) * 16 + q * 4;
      int off = ((it >> 1) * 64 + (col + 16 * (kl >> 3))) * 8 + (kl & 7);
      *(bf16x4*)(sGw + off) = gp;
    }
    mpart += __shfl_xor(mpart, 16, 64); mpart += __shfl_xor(mpart, 32, 64);
    spart += __shfl_xor(spart, 16, 64); spart += __shfl_xor(spart, 32, 64);
    if (lane < 16) { sMSw[lane] = mpart; sMSw[16 + lane] = spart; }
    // phase B: wave-private dependency on sGw/sMSw -> no barrier needed
    for (int dt = 0; dt < 4; dt++) {
      f32x4 acc = {0, 0, 0, 0};
#pragma unroll
      for (int kt = 0; kt < 7; kt++) {
        bf16x8 ga = *(bf16x8*)(sGw + (kt * 64 + lane) * 8);
        bf16x8 ub = *(bf16x8*)(sUAT + ((kt * 4 + dt) * 64 + lane) * 8);
        acc = __builtin_amdgcn_mfma_f32_16x16x32_bf16(ga, ub, acc, 0, 0, 0);
      }
      int d = dt * 16 + col;
      float wd = lw[d], bia = lb[d];
#pragma unroll
      for (int r = 0; r < 4; r++) {
        int jl = q * 4 + r, jg = jt * 16 + jl;
        if (jg < NI) {
          float m = sMSw[jl], S = sMSw[16 + jl];
          int cn = jt * 128 + (d >> 5) * 64 + ((d >> 3) & 3) * 16 + (jg & 15);
          float uajd = bf2fs(sUA[cn * 8 + (d & 7)]);
          float att = wd * (uajd * acc[r] - m) + bia * S;
          out[(size_t)(b * 201 + 1 + jg) * 64 + d] = leaky(att);
        }
      }
    }
  }
}

extern "C" void kernel_launch(void* const* d_in, const int* in_sizes, int n_in,
                              void* d_out, int out_size, void* d_ws, size_t ws_size,
                              hipStream_t stream) {
  const float* emb = (const float*)d_in[0];
  const float* lw  = (const float*)d_in[1];
  const float* lb  = (const float*)d_in[2];
  const float* W1  = (const float*)d_in[3];
  const float* W1b = (const float*)d_in[4];
  const float* W2  = (const float*)d_in[5];
  const float* W2b = (const float*)d_in[6];
  const float* a1  = (const float*)d_in[7];
  const float* a1b = (const float*)d_in[8];
  const float* a2  = (const float*)d_in[9];
  const float* a2b = (const float*)d_in[10];
  float* out = (float*)d_out;

  gat_fused<<<dim3(BB), dim3(512), 0, stream>>>(emb, lw, lb, W1, W1b, W2, W2b,
                                                a1, a1b, a2, a2b, out);
}

// Round 3
// 94.479 us; speedup vs baseline: 1.3923x; 1.3923x over previous
//
#include <hip/hip_runtime.h>
#include <hip/hip_bf16.h>

#define LN_EPS 1e-5f
#define BB 32        // batch
#define NI 200       // attended nodes
#define DD 64        // feature dim

typedef __attribute__((ext_vector_type(8))) short bf16x8;
typedef __attribute__((ext_vector_type(4))) short bf16x4;
typedef __attribute__((ext_vector_type(4))) float f32x4;

__device__ __forceinline__ float leaky(float x) { return fmaxf(x, 0.01f * x); }
__device__ __forceinline__ short f2bf(float x) {
  __hip_bfloat16 h = __float2bfloat16(x);
  return *reinterpret_cast<short*>(&h);
}
__device__ __forceinline__ float bf2fs(short s) {
  unsigned u = ((unsigned)(unsigned short)s) << 16;
  return __uint_as_float(u);
}

__device__ __forceinline__ void reduce2(float& a, float& b) {
#pragma unroll
  for (int m = 1; m < 64; m <<= 1) { a += __shfl_xor(a, m, 64); b += __shfl_xor(b, m, 64); }
}
__device__ __forceinline__ void reduce3(float& a, float& b, float& c) {
#pragma unroll
  for (int m = 1; m < 64; m <<= 1) {
    a += __shfl_xor(a, m, 64); b += __shfl_xor(b, m, 64); c += __shfl_xor(c, m, 64);
  }
}
__device__ __forceinline__ void rmax2(float& a, float& b) {
#pragma unroll
  for (int m = 1; m < 64; m <<= 1) {
    a = fmaxf(a, __shfl_xor(a, m, 64));
    b = fmaxf(b, __shfl_xor(b, m, 64));
  }
}

// ---------------- LDS carve (bytes) ----------------
// Offset-0 region is time-shared: preamble uses it as sY = f32[202][stride 65]
// (raw emb, then normalized in place); phase 3 reuses it as two half-shared
// G frag buffers (7168 B each). sY is dead by then.
#define SM_G    0         // 52544 B (sY f32[202][65] = 52520)
#define SM_UA   52544     // 26624 B  bf16 node-major frags
#define SM_UA2  79168     // 26624 B  squared frags (precomputed once)
#define SM_UAT  105792    // 28672 B  bf16 d-major frags
#define SM_ST   134464    // 4992 B   f32[208][6] {base1,rm1,rden1,base2,rm2,rden2}
#define SM_KV   139456    // 1664 B   f32[2][208] sk per head
#define SM_V    141120    // 1536 B   f32[6][64]  {v1q,v1k,v2q,v2k,vi1,vi2}
#define SM_PART 142656    // 1024 B   f32[2 halves][4 wq][2][16] m/S partials
#define SM_WMX  143680    // 64 B     f32[8][2] per-wave sk maxes
#define SM_MISC 143744    // 32 B     c0..c5, t1full, t2full
#define SM_LN   143776    // 1632 B   f32[202][2] {mu, rinv}
#define SM_TOTAL 145408

// Grid (7, BB) x 512. Block (bx,b): preamble (duplicated per bx, chain-light),
// then old-kY phase 3: half h owns j-tile bx*2+h, 4 waves/half split i-tiles.
__global__ void __launch_bounds__(512, 1)
gat_fused(const float* __restrict__ emb,
          const float* __restrict__ lw,
          const float* __restrict__ lb,
          const float* __restrict__ W1,
          const float* __restrict__ W1b,
          const float* __restrict__ W2,
          const float* __restrict__ W2b,
          const float* __restrict__ a1,
          const float* __restrict__ a1b,
          const float* __restrict__ a2,
          const float* __restrict__ a2b,
          float* __restrict__ out) {
  __shared__ __align__(16) char smem[SM_TOTAL];
  float* sY   = (float*)(smem + SM_G);
  short* sUA  = (short*)(smem + SM_UA);
  short* sUA2 = (short*)(smem + SM_UA2);
  short* sUAT = (short*)(smem + SM_UAT);
  float* sST  = (float*)(smem + SM_ST);
  float* sKV  = (float*)(smem + SM_KV);
  float* sV   = (float*)(smem + SM_V);
  float* sPart = (float*)(smem + SM_PART);
  float* wmx  = (float*)(smem + SM_WMX);
  float* sMisc = (float*)(smem + SM_MISC);
  float* sLN  = (float*)(smem + SM_LN);

  int b = blockIdx.y, bx = blockIdx.x, tid = threadIdx.x;
  int wv = tid >> 6, lane = tid & 63, q = lane >> 4, col = lane & 15;

  // ---- phase 1: stage raw emb -> sY (coalesced); wave-specialized projections ----
  for (int idx = tid; idx < 202 * 16; idx += 512) {
    int r = idx >> 4, qd = (idx & 15) << 2;
    f32x4 v = *(const f32x4*)(emb + ((size_t)b * 202 + r) * 64 + qd);
    float* dst = sY + r * 65 + qd;
    dst[0] = v.x; dst[1] = v.y; dst[2] = v.z; dst[3] = v.w;
  }
  if (wv == 0) {
    float p0 = 0, p1 = 0;
#pragma unroll 8
    for (int d = 0; d < 64; d++) {
      float x = W1[d * 64 + lane];
      p0 = fmaf(x, a1[d], p0); p1 = fmaf(x, a1[64 + d], p1);
    }
    sV[0 * 64 + lane] = p0; sV[1 * 64 + lane] = p1;
  } else if (wv == 1) {
    float p0 = 0, p1 = 0;
#pragma unroll 8
    for (int d = 0; d < 64; d++) {
      float x = W2[d * 64 + lane];
      p0 = fmaf(x, a2[d], p0); p1 = fmaf(x, a2[64 + d], p1);
    }
    sV[2 * 64 + lane] = p0; sV[3 * 64 + lane] = p1;
  } else if (wv == 2) {
    float p = 0;
#pragma unroll 8
    for (int d = 0; d < 64; d++) p = fmaf(W1[d * 64 + lane], a1[128 + d], p);
    sV[4 * 64 + lane] = p;
    float c0 = W1b[lane] * a1[lane];
    float c1 = W1b[lane] * a1[64 + lane];
    float c2 = W1b[lane] * a1[128 + lane];
    reduce3(c0, c1, c2);
    if (lane == 0) { sMisc[0] = c0; sMisc[1] = c1; sMisc[2] = c2; }
  } else if (wv == 3) {
    float p = 0;
#pragma unroll 8
    for (int d = 0; d < 64; d++) p = fmaf(W2[d * 64 + lane], a2[128 + d], p);
    sV[5 * 64 + lane] = p;
    float c3 = W2b[lane] * a2[lane];
    float c4 = W2b[lane] * a2[64 + lane];
    float c5 = W2b[lane] * a2[128 + lane];
    reduce3(c3, c4, c5);
    if (lane == 0) { sMisc[3] = c3; sMisc[4] = c4; sMisc[5] = c5; }
  }
  __syncthreads();

  // ---- phase 2: per-row LN stats, 8 threads/row (chain-light) ----
  {
    int o = tid & 7, rr = tid >> 3;
#pragma unroll
    for (int r0 = 0; r0 < 256; r0 += 64) {
      int r = r0 + rr;
      float s = 0.f, s2 = 0.f;
      if (r < 202) {
        const float* xr = sY + r * 65 + o * 8;
#pragma unroll
        for (int k = 0; k < 8; k++) { float x = xr[k]; s += x; s2 = fmaf(x, x, s2); }
      }
#pragma unroll
      for (int m = 1; m < 8; m <<= 1) {
        s += __shfl_xor(s, m, 64); s2 += __shfl_xor(s2, m, 64);
      }
      if (r < 202 && o == 0) {
        float mu = s * (1.f / 64);
        float var = fmaxf(s2 * (1.f / 64) - mu * mu, 0.f);
        sLN[r * 2] = mu;
        sLN[r * 2 + 1] = rsqrtf(var + LN_EPS);
      }
    }
  }
  __syncthreads();

  // ---- phase 3: normalize sY in place (elementwise, chain-free) ----
  {
    int d = tid & 63;
    float w = lw[d], bi = lb[d];
    for (int idx = tid; idx < 202 * 64; idx += 512) {
      int r = idx >> 6;
      float mu = sLN[r * 2], rinv = sLN[r * 2 + 1];
      float x = sY[r * 65 + d];
      sY[r * 65 + d] = (x - mu) * rinv * w + bi;
    }
  }
  __syncthreads();

  // ---- phase 4: frags, score dots, out row 0, t-dots, pads ----
  if (wv == 0) {
    float u0 = sY[lane];
    float iid = sY[65 + lane];
    out[(size_t)(b * 201) * 64 + lane] = leaky(u0 * iid);
    float q0 = iid * sV[4 * 64 + lane], q1 = iid * sV[5 * 64 + lane];
    reduce2(q0, q1);
    if (lane == 0) {
      sMisc[6] = q0 + sMisc[2] + a1b[0];   // t1 = iid.vi1 + c2 + ab1
      sMisc[7] = q1 + sMisc[5] + a2b[0];   // t2 = iid.vi2 + c5 + ab2
    }
  }
  // node-major frags + squared frags
  for (int idx = tid; idx < 1664; idx += 512) {
    int itile = idx >> 7, rem = idx & 127, kh = rem >> 6, ln = rem & 63;
    int node = itile * 16 + (ln & 15);
    int dbase = kh * 32 + (ln >> 4) * 8;
    bf16x8 pk, pk2;
    if (node < NI) {
      const float* yr = sY + (2 + node) * 65 + dbase;
#pragma unroll
      for (int k = 0; k < 8; k++) {
        float v = sY[dbase + k] * yr[k];      // u[d] * ln[node][d]
        short h = f2bf(v);
        pk[k] = h;
        float f = bf2fs(h);
        pk2[k] = f2bf(f * f);
      }
    } else {
#pragma unroll
      for (int k = 0; k < 8; k++) { pk[k] = 0; pk2[k] = 0; }
    }
    *(bf16x8*)(sUA + idx * 8) = pk;
    *(bf16x8*)(sUA2 + idx * 8) = pk2;
  }
  // d-major frags
  {
    int d = tid & 63, ir = (tid >> 6) & 3, ph = tid >> 8;
    float ud = sY[d];
    for (int p = ph; p < 7; p += 2) {
      int i0 = p * 32 + ir * 8;
      bf16x8 pk;
#pragma unroll
      for (int uu = 0; uu < 8; uu++) {
        int node = i0 + uu;
        pk[uu] = (node < NI) ? f2bf(ud * sY[(2 + node) * 65 + d]) : (short)0;
      }
      int off = ((p * 4 + (d >> 4)) * 64 + ((d & 15) + 16 * ir)) * 8;
      *(bf16x8*)(sUAT + off) = pk;
    }
  }
  // score dots: 8 threads/row, u0*v preloaded
  {
    int o = tid & 7, rr = tid >> 3;
    float uv0[8], uv1[8], uv2[8], uv3[8];
#pragma unroll
    for (int k = 0; k < 8; k++) {
      float u0k = sY[o * 8 + k];
      uv0[k] = u0k * sV[0 * 64 + o * 8 + k];
      uv1[k] = u0k * sV[1 * 64 + o * 8 + k];
      uv2[k] = u0k * sV[2 * 64 + o * 8 + k];
      uv3[k] = u0k * sV[3 * 64 + o * 8 + k];
    }
#pragma unroll
    for (int r0 = 0; r0 < 256; r0 += 64) {
      int i = r0 + rr;
      float p0 = 0, p1 = 0, p2 = 0, p3 = 0;
      if (i < NI) {
        const float* yr = sY + (2 + i) * 65 + o * 8;
#pragma unroll
        for (int k = 0; k < 8; k++) {
          float y = yr[k];
          p0 = fmaf(y, uv0[k], p0); p1 = fmaf(y, uv1[k], p1);
          p2 = fmaf(y, uv2[k], p2); p3 = fmaf(y, uv3[k], p3);
        }
      }
#pragma unroll
      for (int m = 1; m < 8; m <<= 1) {
        p0 += __shfl_xor(p0, m, 64); p1 += __shfl_xor(p1, m, 64);
        p2 += __shfl_xor(p2, m, 64); p3 += __shfl_xor(p3, m, 64);
      }
      if (i < NI && o == 0) {
        sST[i * 6 + 0] = p0 + sMisc[0];    // sq1 + c0 (t1 added later)
        sST[i * 6 + 3] = p2 + sMisc[3];    // sq2 + c3
        sKV[0 * 208 + i] = p1 + sMisc[1];  // sk1 + c1
        sKV[1 * 208 + i] = p3 + sMisc[4];  // sk2 + c4
      }
    }
  }
  // pad rows 200..207: zero stats (-> g=0) and zero sk (finite)
  if (tid < 48) sST[1200 + tid] = 0.f;
  if (tid < 16) sKV[(tid >> 3) * 208 + 200 + (tid & 7)] = 0.f;
  __syncthreads();

  // ---- phase 5: block max of sk ----
  {
    float m1 = (tid < NI) ? sKV[tid] : -3e38f;
    float m2 = (tid < NI) ? sKV[208 + tid] : -3e38f;
    rmax2(m1, m2);
    if (lane == 0) { wmx[wv * 2] = m1; wmx[wv * 2 + 1] = m2; }
  }
  __syncthreads();

  // ---- phase 6: softmax stats (4-accumulator denominator) ----
  {
    int sh = -1, si = 0;
    if (tid < NI) { sh = 0; si = tid; }
    else if (tid >= 256 && tid < 256 + NI) { sh = 1; si = tid - 256; }
    if (sh >= 0) {
      float mx = -3e38f;
#pragma unroll
      for (int k = 0; k < 8; k++) mx = fmaxf(mx, wmx[k * 2 + sh]);
      float* st = sST + si * 6;
      float base = st[sh * 3] + sMisc[6 + sh];   // add t-term
      st[sh * 3] = base;
      float rm = leaky(base + mx);               // leaky monotone
      const float* skh = sKV + sh * 208;
      float d0 = 0, d1 = 0, d2 = 0, d3 = 0;
      for (int j = 0; j < NI; j += 4) {
        float s0 = base + skh[j + 0]; d0 += __expf(fmaxf(s0, 0.01f * s0) - rm);
        float s1 = base + skh[j + 1]; d1 += __expf(fmaxf(s1, 0.01f * s1) - rm);
        float s2 = base + skh[j + 2]; d2 += __expf(fmaxf(s2, 0.01f * s2) - rm);
        float s3 = base + skh[j + 3]; d3 += __expf(fmaxf(s3, 0.01f * s3) - rm);
      }
      st[sh * 3 + 1] = rm;
      st[sh * 3 + 2] = 1.0f / ((d0 + d1) + (d2 + d3));
    }
  }
  __syncthreads();

  // ---- phase 7: A (S/T MFMAs + epilogue -> G) — sY is dead, G overlays it ----
  int half = wv >> 2, wq = wv & 3;
  int jt = bx * 2 + half;
  bool act = (jt < 13);
  short* sG0 = (short*)(smem + SM_G);
  short* sG1 = (short*)(smem + SM_G + 7168);
  short* sGh = half ? sG1 : sG0;
  float* sPh = sPart + half * 128;    // [4 wq][2][16]

  if (tid < 128) ((int*)sG0)[1664 + tid] = 0;             // zero k-tail i=208..223
  else if (tid < 256) ((int*)sG1)[1664 + (tid - 128)] = 0;

  if (act) {
    bf16x8 bf0 = *(bf16x8*)(sUA + ((jt * 2 + 0) * 64 + lane) * 8);
    bf16x8 bf1 = *(bf16x8*)(sUA + ((jt * 2 + 1) * 64 + lane) * 8);
    bf16x8 b2f0 = *(bf16x8*)(sUA2 + ((jt * 2 + 0) * 64 + lane) * 8);
    bf16x8 b2f1 = *(bf16x8*)(sUA2 + ((jt * 2 + 1) * 64 + lane) * 8);
    int jglob = jt * 16 + col;
    float skj1 = sKV[jglob], skj2 = sKV[208 + jglob];
    float mpart = 0.f, spart = 0.f;
    for (int it = wq; it < 13; it += 4) {
      bf16x8 af0 = *(bf16x8*)(sUA + ((it * 2 + 0) * 64 + lane) * 8);
      bf16x8 af1 = *(bf16x8*)(sUA + ((it * 2 + 1) * 64 + lane) * 8);
      bf16x8 a2f0 = *(bf16x8*)(sUA2 + ((it * 2 + 0) * 64 + lane) * 8);
      bf16x8 a2f1 = *(bf16x8*)(sUA2 + ((it * 2 + 1) * 64 + lane) * 8);
      f32x4 s = {0, 0, 0, 0}, t = {0, 0, 0, 0};
      s = __builtin_amdgcn_mfma_f32_16x16x32_bf16(af0, bf0, s, 0, 0, 0);
      s = __builtin_amdgcn_mfma_f32_16x16x32_bf16(af1, bf1, s, 0, 0, 0);
      t = __builtin_amdgcn_mfma_f32_16x16x32_bf16(a2f0, b2f0, t, 0, 0, 0);
      t = __builtin_amdgcn_mfma_f32_16x16x32_bf16(a2f1, b2f1, t, 0, 0, 0);
      bf16x4 gp;
#pragma unroll
      for (int r = 0; r < 4; r++) {
        int i = it * 16 + q * 4 + r;
        const float* st = sST + i * 6;
        float mu = s[r] * (1.f / 64);
        float var = fmaxf(t[r] * (1.f / 64) - mu * mu, 0.f);
        float inv = rsqrtf(var + LN_EPS);
        float sc1 = st[0] + skj1;
        float e1 = __expf(fmaxf(sc1, 0.01f * sc1) - st[1]) * st[2];
        float sc2 = st[3] + skj2;
        float e2 = __expf(fmaxf(sc2, 0.01f * sc2) - st[4]) * st[5];
        float c = 0.5f * (e1 + e2);
        float g = c * inv;
        mpart = fmaf(g, mu, mpart);
        spart += c;
        gp[r] = f2bf(g);
      }
      int kl = (it & 1) * 16 + q * 4;
      int off = ((it >> 1) * 64 + (col + 16 * (kl >> 3))) * 8 + (kl & 7);
      *(bf16x4*)(sGh + off) = gp;
    }
    mpart += __shfl_xor(mpart, 16, 64); mpart += __shfl_xor(mpart, 32, 64);
    spart += __shfl_xor(spart, 16, 64); spart += __shfl_xor(spart, 32, 64);
    if (lane < 16) {
      sPh[(wq * 2 + 0) * 16 + lane] = mpart;
      sPh[(wq * 2 + 1) * 16 + lane] = spart;
    }
  }
  __syncthreads();

  // ---- phase 8: B (H = G^T * UA + output epilogue) ----
  if (act) {
    f32x4 acc = {0, 0, 0, 0};
#pragma unroll
    for (int kt = 0; kt < 7; kt++) {
      bf16x8 ga = *(bf16x8*)(sGh + (kt * 64 + lane) * 8);
      bf16x8 ub = *(bf16x8*)(sUAT + ((kt * 4 + wq) * 64 + lane) * 8);
      acc = __builtin_amdgcn_mfma_f32_16x16x32_bf16(ga, ub, acc, 0, 0, 0);
    }
    int d = wq * 16 + col;
    float w = lw[d], bia = lb[d];
#pragma unroll
    for (int r = 0; r < 4; r++) {
      int jl = q * 4 + r, jg = jt * 16 + jl;
      if (jg < NI) {
        float m = sPh[0 * 16 + jl] + sPh[2 * 16 + jl] +
                  sPh[4 * 16 + jl] + sPh[6 * 16 + jl];
        float S = sPh[1 * 16 + jl] + sPh[3 * 16 + jl] +
                  sPh[5 * 16 + jl] + sPh[7 * 16 + jl];
        int cn = jt * 128 + (d >> 5) * 64 + ((d >> 3) & 3) * 16 + (jg & 15);
        float uajd = bf2fs(sUA[cn * 8 + (d & 7)]);
        float att = w * (uajd * acc[r] - m) + bia * S;
        out[(size_t)(b * 201 + 1 + jg) * 64 + d] = leaky(att);
      }
    }
  }
}

extern "C" void kernel_launch(void* const* d_in, const int* in_sizes, int n_in,
                              void* d_out, int out_size, void* d_ws, size_t ws_size,
                              hipStream_t stream) {
  const float* emb = (const float*)d_in[0];
  const float* lw  = (const float*)d_in[1];
  const float* lb  = (const float*)d_in[2];
  const float* W1  = (const float*)d_in[3];
  const float* W1b = (const float*)d_in[4];
  const float* W2  = (const float*)d_in[5];
  const float* W2b = (const float*)d_in[6];
  const float* a1  = (const float*)d_in[7];
  const float* a1b = (const float*)d_in[8];
  const float* a2  = (const float*)d_in[9];
  const float* a2b = (const float*)d_in[10];
  float* out = (float*)d_out;

  gat_fused<<<dim3(7, BB), dim3(512), 0, stream>>>(emb, lw, lb, W1, W1b, W2, W2b,
                                                   a1, a1b, a2, a2b, out);
}

// Round 5
// 93.897 us; speedup vs baseline: 1.4009x; 1.0062x over previous
//
#include <hip/hip_runtime.h>
#include <hip/hip_bf16.h>

#define LN_EPS 1e-5f
#define BB 32        // batch
#define NI 200       // attended nodes
#define DD 64        // feature dim

typedef __attribute__((ext_vector_type(8))) short bf16x8;
typedef __attribute__((ext_vector_type(4))) short bf16x4;
typedef __attribute__((ext_vector_type(4))) float f32x4;

__device__ __forceinline__ float leaky(float x) { return fmaxf(x, 0.01f * x); }
__device__ __forceinline__ short f2bf(float x) {
  __hip_bfloat16 h = __float2bfloat16(x);
  return *reinterpret_cast<short*>(&h);
}
__device__ __forceinline__ float bf2fs(short s) {
  unsigned u = ((unsigned)(unsigned short)s) << 16;
  return __uint_as_float(u);
}

__device__ __forceinline__ void reduce2(float& a, float& b) {
#pragma unroll
  for (int m = 1; m < 64; m <<= 1) { a += __shfl_xor(a, m, 64); b += __shfl_xor(b, m, 64); }
}
__device__ __forceinline__ void reduce3(float& a, float& b, float& c) {
#pragma unroll
  for (int m = 1; m < 64; m <<= 1) {
    a += __shfl_xor(a, m, 64); b += __shfl_xor(b, m, 64); c += __shfl_xor(c, m, 64);
  }
}
__device__ __forceinline__ void rmax2(float& a, float& b) {
#pragma unroll
  for (int m = 1; m < 64; m <<= 1) {
    a = fmaxf(a, __shfl_xor(a, m, 64));
    b = fmaxf(b, __shfl_xor(b, m, 64));
  }
}

// ---------------- workspace layout (bytes) ----------------
// Per-b staged block (order MUST match k3's LDS stage region):
//   UA (26624) | UA2 (26624) | UAT (28672) | ST f32[208][6] (4992) | KV f32[2][208] (1664)
#define WB_STRIDE 88576
#define WB_UA2    26624
#define WB_UAT    53248
#define WB_ST     81920
#define WB_KV     86912
// Extra (not staged):
#define WX_RAWD   2834432        // f32[BB][208][4] raw dots {p0,p1,p2,p3}
#define WX_TD     2940928        // f32[BB][2] raw iid*vi dots
#define WX_CR     2941184        // f32[BB][6] raw creds

// ============ k1: per-(i-tile, b) LN + frags + raw dots ============
__global__ void __launch_bounds__(256)
gat_k1(const float* __restrict__ emb,
       const float* __restrict__ lw,
       const float* __restrict__ lb,
       const float* __restrict__ W1,
       const float* __restrict__ W1b,
       const float* __restrict__ W2,
       const float* __restrict__ W2b,
       const float* __restrict__ a1,
       const float* __restrict__ a2,
       float* __restrict__ ws,
       float* __restrict__ out) {
  __shared__ float sE[18 * 65];   // rows: 0,1 = u,iid; 2..17 = nodes it*16..+15
  __shared__ float sV[4 * 64];    // v1q,v1k,v2q,v2k
  __shared__ float sVi[2 * 64];   // vi1, vi2 (it==0 only)
  __shared__ float sLN[18 * 2];

  int b = blockIdx.y, it = blockIdx.x, tid = threadIdx.x;
  int wv = tid >> 6, lane = tid & 63;

  char* wsb = (char*)ws + (size_t)b * WB_STRIDE;
  short* wUA  = (short*)wsb;
  short* wUA2 = (short*)(wsb + WB_UA2);
  short* wUAT = (short*)(wsb + WB_UAT);
  float* wRAW = (float*)((char*)ws + WX_RAWD) + (size_t)b * 832;
  float* wTD  = (float*)((char*)ws + WX_TD) + b * 2;
  float* wCR  = (float*)((char*)ws + WX_CR) + b * 6;

  // stage 18 rows of raw emb (zeros for nonexistent rows)
  for (int idx = tid; idx < 288; idx += 256) {
    int r = idx >> 4, qd = (idx & 15) << 2;
    int g = (r < 2) ? r : 2 + it * 16 + (r - 2);
    f32x4 v = {0, 0, 0, 0};
    if (g <= 201) v = *(const f32x4*)(emb + ((size_t)b * 202 + g) * 64 + qd);
    float* dst = sE + r * 65 + qd;
    dst[0] = v.x; dst[1] = v.y; dst[2] = v.z; dst[3] = v.w;
  }
  // wave-specialized projections
  if (wv == 0) {
    float p0 = 0, p1 = 0;
#pragma unroll 8
    for (int d = 0; d < 64; d++) {
      float x = W1[d * 64 + lane];
      p0 = fmaf(x, a1[d], p0); p1 = fmaf(x, a1[64 + d], p1);
    }
    sV[0 * 64 + lane] = p0; sV[1 * 64 + lane] = p1;
  } else if (wv == 1) {
    float p0 = 0, p1 = 0;
#pragma unroll 8
    for (int d = 0; d < 64; d++) {
      float x = W2[d * 64 + lane];
      p0 = fmaf(x, a2[d], p0); p1 = fmaf(x, a2[64 + d], p1);
    }
    sV[2 * 64 + lane] = p0; sV[3 * 64 + lane] = p1;
  } else if (wv == 2 && it == 0) {
    float p = 0;
#pragma unroll 8
    for (int d = 0; d < 64; d++) p = fmaf(W1[d * 64 + lane], a1[128 + d], p);
    sVi[lane] = p;
    float c0 = W1b[lane] * a1[lane];
    float c1 = W1b[lane] * a1[64 + lane];
    float c2 = W1b[lane] * a1[128 + lane];
    reduce3(c0, c1, c2);
    if (lane == 0) { wCR[0] = c0; wCR[1] = c1; wCR[2] = c2; }
  } else if (wv == 3 && it == 0) {
    float p = 0;
#pragma unroll 8
    for (int d = 0; d < 64; d++) p = fmaf(W2[d * 64 + lane], a2[128 + d], p);
    sVi[64 + lane] = p;
    float c3 = W2b[lane] * a2[lane];
    float c4 = W2b[lane] * a2[64 + lane];
    float c5 = W2b[lane] * a2[128 + lane];
    reduce3(c3, c4, c5);
    if (lane == 0) { wCR[3] = c3; wCR[4] = c4; wCR[5] = c5; }
  }
  __syncthreads();

  // LN stats: 8 threads/row
  {
    int o = tid & 7, rr = tid >> 3;
    float s = 0.f, s2 = 0.f;
    if (rr < 18) {
      const float* xr = sE + rr * 65 + o * 8;
#pragma unroll
      for (int k = 0; k < 8; k++) { float x = xr[k]; s += x; s2 = fmaf(x, x, s2); }
    }
#pragma unroll
    for (int m = 1; m < 8; m <<= 1) {
      s += __shfl_xor(s, m, 64); s2 += __shfl_xor(s2, m, 64);
    }
    if (rr < 18 && o == 0) {
      float mu = s * (1.f / 64);
      float var = fmaxf(s2 * (1.f / 64) - mu * mu, 0.f);
      sLN[rr * 2] = mu;
      sLN[rr * 2 + 1] = rsqrtf(var + LN_EPS);
    }
  }
  __syncthreads();

  // normalize in place
  {
    int d = tid & 63;
    float w = lw[d], bi = lb[d];
    for (int idx = tid; idx < 18 * 64; idx += 256) {
      int r = idx >> 6;
      float mu = sLN[r * 2], rinv = sLN[r * 2 + 1];
      float x = sE[r * 65 + d];
      sE[r * 65 + d] = (x - mu) * rinv * w + bi;
    }
  }
  __syncthreads();

  // out row 0 + raw t-dots (block it==0)
  if (it == 0 && wv == 2) {
    float u0 = sE[lane], iid = sE[65 + lane];
    out[(size_t)(b * 201) * 64 + lane] = leaky(u0 * iid);
    float q0 = iid * sVi[lane], q1 = iid * sVi[64 + lane];
    reduce2(q0, q1);
    if (lane == 0) { wTD[0] = q0; wTD[1] = q1; }
  }
  // frag slices
  if (tid < 128) {
    // node-major + squared frags for this i-tile
    int rem = tid, kh = rem >> 6, ln = rem & 63;
    int lnode = ln & 15, g = it * 16 + lnode;
    int dbase = kh * 32 + (ln >> 4) * 8, lr = 2 + lnode;
    bf16x8 pk, pk2;
    if (g < NI) {
      const float* yr = sE + lr * 65 + dbase;
#pragma unroll
      for (int k = 0; k < 8; k++) {
        float v = sE[dbase + k] * yr[k];
        short h = f2bf(v);
        pk[k] = h;
        float f = bf2fs(h);
        pk2[k] = f2bf(f * f);
      }
    } else {
#pragma unroll
      for (int k = 0; k < 8; k++) { pk[k] = 0; pk2[k] = 0; }
    }
    *(bf16x8*)(wUA + (it * 128 + rem) * 8) = pk;
    *(bf16x8*)(wUA2 + (it * 128 + rem) * 8) = pk2;
  } else {
    // d-major frag half-slice: p = it>>1, ir in {0,1}+2*(it&1)
    int tid2 = tid - 128, d = tid2 & 63;
    int ir = (it & 1) * 2 + (tid2 >> 6), p = it >> 1;
    int i0 = p * 32 + ir * 8, ln0 = i0 - it * 16;   // 0 or 8
    float ud = sE[d];
    bf16x8 pk;
#pragma unroll
    for (int uu = 0; uu < 8; uu++) {
      int node = i0 + uu;
      pk[uu] = (node < NI) ? f2bf(ud * sE[(2 + ln0 + uu) * 65 + d]) : (short)0;
    }
    int off = ((p * 4 + (d >> 4)) * 64 + ((d & 15) + 16 * ir)) * 8;
    *(bf16x8*)(wUAT + off) = pk;
    if (it == 12) {
      // BUGFIX: p=6, ir in {2,3} (nodes 208..223) is produced by no block
      // (it=13 doesn't exist). Zero-fill so k3 never stages poisoned ws.
      bf16x8 z;
#pragma unroll
      for (int uu = 0; uu < 8; uu++) z[uu] = 0;
      int off2 = ((p * 4 + (d >> 4)) * 64 + ((d & 15) + 16 * (ir + 2))) * 8;
      *(bf16x8*)(wUAT + off2) = z;
    }
  }
  // raw score dots: 8 threads/row, 16 rows
  if (tid < 128) {
    int o = tid & 7, rr = tid >> 3;
    int i = it * 16 + rr;
    if (i < NI) {
      float uv0[8], uv1[8], uv2[8], uv3[8];
#pragma unroll
      for (int k = 0; k < 8; k++) {
        float u0k = sE[o * 8 + k];
        uv0[k] = u0k * sV[0 * 64 + o * 8 + k];
        uv1[k] = u0k * sV[1 * 64 + o * 8 + k];
        uv2[k] = u0k * sV[2 * 64 + o * 8 + k];
        uv3[k] = u0k * sV[3 * 64 + o * 8 + k];
      }
      const float* yr = sE + (2 + rr) * 65 + o * 8;
      float p0 = 0, p1 = 0, p2 = 0, p3 = 0;
#pragma unroll
      for (int k = 0; k < 8; k++) {
        float y = yr[k];
        p0 = fmaf(y, uv0[k], p0); p1 = fmaf(y, uv1[k], p1);
        p2 = fmaf(y, uv2[k], p2); p3 = fmaf(y, uv3[k], p3);
      }
#pragma unroll
      for (int m = 1; m < 8; m <<= 1) {
        p0 += __shfl_xor(p0, m, 64); p1 += __shfl_xor(p1, m, 64);
        p2 += __shfl_xor(p2, m, 64); p3 += __shfl_xor(p3, m, 64);
      }
      if (o == 0) {
        wRAW[i * 4 + 0] = p0; wRAW[i * 4 + 1] = p1;
        wRAW[i * 4 + 2] = p2; wRAW[i * 4 + 3] = p3;
      }
    }
  }
}

// ============ k2: softmax stats (once per b, row-sliced) ============
__global__ void __launch_bounds__(512)
gat_k2(float* __restrict__ ws,
       const float* __restrict__ a1b,
       const float* __restrict__ a2b) {
  __shared__ float skv[2 * 208];
  __shared__ float wmx[16];
  int b = blockIdx.y, bx = blockIdx.x, tid = threadIdx.x;
  int wv = tid >> 6, lane = tid & 63;

  char* wsb = (char*)ws + (size_t)b * WB_STRIDE;
  float* wST = (float*)(wsb + WB_ST);
  float* wKV = (float*)(wsb + WB_KV);
  const float* wRAW = (const float*)((char*)ws + WX_RAWD) + (size_t)b * 832;
  const float* wTD  = (const float*)((char*)ws + WX_TD) + b * 2;
  const float* wCR  = (const float*)((char*)ws + WX_CR) + b * 6;

  float c0 = wCR[0], c1 = wCR[1], c2 = wCR[2];
  float c3 = wCR[3], c4 = wCR[4], c5 = wCR[5];
  float t1 = (wTD[0] + c2) + a1b[0];
  float t2 = (wTD[1] + c5) + a2b[0];

  if (tid < 208) {
    float s1 = 0.f, s2 = 0.f;
    if (tid < NI) {
      s1 = wRAW[tid * 4 + 1] + c1;
      s2 = wRAW[tid * 4 + 3] + c4;
    }
    skv[tid] = s1; skv[208 + tid] = s2;
    if (bx == 0) { wKV[tid] = s1; wKV[208 + tid] = s2; }
  }
  __syncthreads();

  // block max of sk over real j
  {
    float m1 = (tid < NI) ? skv[tid] : -3e38f;
    float m2 = (tid < NI) ? skv[208 + tid] : -3e38f;
    rmax2(m1, m2);
    if (lane == 0) { wmx[wv * 2] = m1; wmx[wv * 2 + 1] = m2; }
  }
  __syncthreads();

  // stats: 4 threads per (row, head); this block covers rows [bx*52, bx*52+52)
  {
    int o = tid & 3, item = tid >> 2;
    int rl = item >> 1, sh = item & 1;
    if (rl < 52) {
      int r = bx * 52 + rl;
      if (r < 208) {
        float* st = wST + r * 6 + sh * 3;
        if (r < NI) {
          float mx = -3e38f;
#pragma unroll
          for (int k = 0; k < 8; k++) mx = fmaxf(mx, wmx[k * 2 + sh]);
          float base = (wRAW[r * 4 + (sh ? 2 : 0)] + (sh ? c3 : c0)) + (sh ? t2 : t1);
          float rm = leaky(base + mx);
          const float* skh = skv + sh * 208;
          float den = 0.f;
          int j0 = o * 50;
#pragma unroll 5
          for (int j = j0; j < j0 + 50; j++) {
            float s = base + skh[j];
            den += __expf(fmaxf(s, 0.01f * s) - rm);
          }
          den += __shfl_xor(den, 1, 64);
          den += __shfl_xor(den, 2, 64);
          if (o == 0) { st[0] = base; st[1] = rm; st[2] = 1.0f / den; }
        } else if (o == 0) {
          st[0] = 0.f; st[1] = 0.f; st[2] = 0.f;
        }
      }
    }
  }
}

// ============ k3: MFMA phases (staged from ws) ============
// LDS: G (2 x 7168) | staged block (88576, same order as ws) | sPart (1024)
#define L_G1    7168
#define L_STAGE 14336
#define L_UA    14336
#define L_UA2   40960
#define L_UAT   67584
#define L_ST    96256
#define L_KV    101248
#define L_PART  102912
#define L_TOTAL 103936

__global__ void __launch_bounds__(512, 1)
gat_k3(const float* __restrict__ ws,
       const float* __restrict__ lw,
       const float* __restrict__ lb,
       float* __restrict__ out) {
  __shared__ __align__(16) char smem[L_TOTAL];
  short* sUA  = (short*)(smem + L_UA);
  short* sUA2 = (short*)(smem + L_UA2);
  short* sUAT = (short*)(smem + L_UAT);
  float* sST  = (float*)(smem + L_ST);
  float* sKV  = (float*)(smem + L_KV);
  float* sPart = (float*)(smem + L_PART);

  int b = blockIdx.y, bx = blockIdx.x, tid = threadIdx.x;
  int wv = tid >> 6, lane = tid & 63, q = lane >> 4, col = lane & 15;

  // linear stage of the whole per-b block (L2-hot after first block)
  {
    const f32x4* src = (const f32x4*)((const char*)ws + (size_t)b * WB_STRIDE);
    f32x4* dst = (f32x4*)(smem + L_STAGE);
    for (int idx = tid; idx < WB_STRIDE / 16; idx += 512) dst[idx] = src[idx];
  }
  // zero G k-tails (i = 208..223)
  short* sG0 = (short*)smem;
  short* sG1 = (short*)(smem + L_G1);
  if (tid < 128) ((int*)sG0)[1664 + tid] = 0;
  else if (tid < 256) ((int*)sG1)[1664 + (tid - 128)] = 0;
  __syncthreads();

  // ---- phase A: S/T MFMAs + epilogue -> G (half h owns j-tile bx*2+h) ----
  int half = wv >> 2, wq = wv & 3;
  int jt = bx * 2 + half;
  bool act = (jt < 13);
  short* sGh = half ? sG1 : sG0;
  float* sPh = sPart + half * 128;    // [4 wq][2][16]

  if (act) {
    bf16x8 bf0 = *(bf16x8*)(sUA + ((jt * 2 + 0) * 64 + lane) * 8);
    bf16x8 bf1 = *(bf16x8*)(sUA + ((jt * 2 + 1) * 64 + lane) * 8);
    bf16x8 b2f0 = *(bf16x8*)(sUA2 + ((jt * 2 + 0) * 64 + lane) * 8);
    bf16x8 b2f1 = *(bf16x8*)(sUA2 + ((jt * 2 + 1) * 64 + lane) * 8);
    int jglob = jt * 16 + col;
    float skj1 = sKV[jglob], skj2 = sKV[208 + jglob];
    float mpart = 0.f, spart = 0.f;
    for (int it = wq; it < 13; it += 4) {
      bf16x8 af0 = *(bf16x8*)(sUA + ((it * 2 + 0) * 64 + lane) * 8);
      bf16x8 af1 = *(bf16x8*)(sUA + ((it * 2 + 1) * 64 + lane) * 8);
      bf16x8 a2f0 = *(bf16x8*)(sUA2 + ((it * 2 + 0) * 64 + lane) * 8);
      bf16x8 a2f1 = *(bf16x8*)(sUA2 + ((it * 2 + 1) * 64 + lane) * 8);
      f32x4 s = {0, 0, 0, 0}, t = {0, 0, 0, 0};
      s = __builtin_amdgcn_mfma_f32_16x16x32_bf16(af0, bf0, s, 0, 0, 0);
      s = __builtin_amdgcn_mfma_f32_16x16x32_bf16(af1, bf1, s, 0, 0, 0);
      t = __builtin_amdgcn_mfma_f32_16x16x32_bf16(a2f0, b2f0, t, 0, 0, 0);
      t = __builtin_amdgcn_mfma_f32_16x16x32_bf16(a2f1, b2f1, t, 0, 0, 0);
      bf16x4 gp;
#pragma unroll
      for (int r = 0; r < 4; r++) {
        int i = it * 16 + q * 4 + r;
        const float* st = sST + i * 6;
        float mu = s[r] * (1.f / 64);
        float var = fmaxf(t[r] * (1.f / 64) - mu * mu, 0.f);
        float inv = rsqrtf(var + LN_EPS);
        float sc1 = st[0] + skj1;
        float e1 = __expf(fmaxf(sc1, 0.01f * sc1) - st[1]) * st[2];
        float sc2 = st[3] + skj2;
        float e2 = __expf(fmaxf(sc2, 0.01f * sc2) - st[4]) * st[5];
        float c = 0.5f * (e1 + e2);
        float g = c * inv;
        mpart = fmaf(g, mu, mpart);
        spart += c;
        gp[r] = f2bf(g);
      }
      int kl = (it & 1) * 16 + q * 4;
      int off = ((it >> 1) * 64 + (col + 16 * (kl >> 3))) * 8 + (kl & 7);
      *(bf16x4*)(sGh + off) = gp;
    }
    mpart += __shfl_xor(mpart, 16, 64); mpart += __shfl_xor(mpart, 32, 64);
    spart += __shfl_xor(spart, 16, 64); spart += __shfl_xor(spart, 32, 64);
    if (lane < 16) {
      sPh[(wq * 2 + 0) * 16 + lane] = mpart;
      sPh[(wq * 2 + 1) * 16 + lane] = spart;
    }
  }
  __syncthreads();

  // ---- phase B: H = G^T * UA + output epilogue ----
  if (act) {
    f32x4 acc = {0, 0, 0, 0};
#pragma unroll
    for (int kt = 0; kt < 7; kt++) {
      bf16x8 ga = *(bf16x8*)(sGh + (kt * 64 + lane) * 8);
      bf16x8 ub = *(bf16x8*)(sUAT + ((kt * 4 + wq) * 64 + lane) * 8);
      acc = __builtin_amdgcn_mfma_f32_16x16x32_bf16(ga, ub, acc, 0, 0, 0);
    }
    int d = wq * 16 + col;
    float w = lw[d], bia = lb[d];
#pragma unroll
    for (int r = 0; r < 4; r++) {
      int jl = q * 4 + r, jg = jt * 16 + jl;
      if (jg < NI) {
        float m = sPh[0 * 16 + jl] + sPh[2 * 16 + jl] +
                  sPh[4 * 16 + jl] + sPh[6 * 16 + jl];
        float S = sPh[1 * 16 + jl] + sPh[3 * 16 + jl] +
                  sPh[5 * 16 + jl] + sPh[7 * 16 + jl];
        int cn = jt * 128 + (d >> 5) * 64 + ((d >> 3) & 3) * 16 + (jg & 15);
        float uajd = bf2fs(sUA[cn * 8 + (d & 7)]);
        float att = w * (uajd * acc[r] - m) + bia * S;
        out[(size_t)(b * 201 + 1 + jg) * 64 + d] = leaky(att);
      }
    }
  }
}

extern "C" void kernel_launch(void* const* d_in, const int* in_sizes, int n_in,
                              void* d_out, int out_size, void* d_ws, size_t ws_size,
                              hipStream_t stream) {
  const float* emb = (const float*)d_in[0];
  const float* lw  = (const float*)d_in[1];
  const float* lb  = (const float*)d_in[2];
  const float* W1  = (const float*)d_in[3];
  const float* W1b = (const float*)d_in[4];
  const float* W2  = (const float*)d_in[5];
  const float* W2b = (const float*)d_in[6];
  const float* a1  = (const float*)d_in[7];
  const float* a1b = (const float*)d_in[8];
  const float* a2  = (const float*)d_in[9];
  const float* a2b = (const float*)d_in[10];
  float* ws = (float*)d_ws;
  float* out = (float*)d_out;

  gat_k1<<<dim3(13, BB), dim3(256), 0, stream>>>(emb, lw, lb, W1, W1b, W2, W2b,
                                                 a1, a2, ws, out);
  gat_k2<<<dim3(4, BB), dim3(512), 0, stream>>>(ws, a1b, a2b);
  gat_k3<<<dim3(7, BB), dim3(512), 0, stream>>>(ws, lw, lb, out);
}